// Round 17
// baseline (227.399 us; speedup 1.0000x reference)
//
#include <hip/hip_runtime.h>

#define TT 512
#define DD 16
#define HH 30
#define LL 10
#define CHK 8                 // timesteps per chunk (sync granularity)
#define HC  4                 // timesteps per half (inner body)
#define NCH (TT / CHK)        // 64 chunks
#define RING 2                // slots per link; slack = 8..16 timesteps
#define GRP 16                // batches per block = MFMA N
#define BLOCKT (LL * 64)      // 640 threads, wave = layer
#define KPRE 2.885390081777927f   // 2*log2(e)

// sigma table: sigma(d)=1/(2^d+1), d in [-12,12), 6144 entries, step 1/256
#define TBL   6144
#define TSCAL 256.0f
#define TOFF  3072.0f
#define TMAXF 6143.0f

// LDS strides in halfs (links start after the table)
#define CC_H   512
#define HALF_H (HC * CC_H)    // 2048
#define SL_H   (CHK * CC_H)   // 4096
#define LINK_H (RING * SL_H)  // 8192 halfs = 16 KB; 9 links = 147456 B

typedef _Float16 f16x8 __attribute__((ext_vector_type(8)));
typedef _Float16 h2    __attribute__((ext_vector_type(2)));
typedef float    f32x4 __attribute__((ext_vector_type(4)));

union U128 { uint4 u; f16x8 h; h2 p[4]; };

// k-position -> natural neuron permutation (MFMA D == next B-own fragment).
__device__ __forceinline__ int nu_of(int k) {
    return 16 * ((k >> 2) & 1) + 4 * (k >> 3) + (k & 3);
}

// table index for preact d (trans-free): fma + clamp + trunc
__device__ __forceinline__ int sidx(float d) {
    float f = fmaf(d, TSCAL, TOFF);
    f = fminf(fmaxf(f, 0.0f), TMAXF);
    return (int)f;
}

// Busy-poll, no s_sleep: wake latency = one LDS round-trip; SIMDs are idle enough.
__device__ __forceinline__ void wait_ge(unsigned* f, unsigned tgt) {
    while (__hip_atomic_load(f, __ATOMIC_ACQUIRE,
                             __HIP_MEMORY_SCOPE_WORKGROUP) < tgt) {}
}

// Hand-rolled release: order our LDS ops before the LDS flag store, and
// NOTHING else -- never drains vmcnt (wave-0 global prefetch stays in flight).
__device__ __forceinline__ void publish(unsigned* f, unsigned v) {
    __builtin_amdgcn_sched_barrier(0);
    asm volatile("s_waitcnt lgkmcnt(0)" ::: "memory");
    __hip_atomic_store(f, v, __ATOMIC_RELAXED, __HIP_MEMORY_SCOPE_WORKGROUP);
}

__global__ __launch_bounds__(BLOCKT) void rnn_tbl(
    const float* __restrict__ x,   const float* __restrict__ wi0,
    const float* __restrict__ wih, const float* __restrict__ whh,
    const float* __restrict__ bih, const float* __restrict__ bhh,
    const float* __restrict__ fcw, const float* __restrict__ fcb,
    float* __restrict__ out)
{
    extern __shared__ __align__(16) _Float16 sm[];
    _Float16* tbl  = sm;                 // [TBL]
    _Float16* link = sm + TBL;           // [LL-1][RING][CHK][512h]
    const unsigned short* tbu = (const unsigned short*)sm;
    __shared__ unsigned flg[2 * LL];     // [l]=produced, [LL+l]=consumed

    const int tid  = threadIdx.x;
    const int l    = tid >> 6;        // wave == layer
    const int lane = tid & 63;
    const int n    = lane & 15;       // batch-in-group
    const int qq   = lane >> 4;       // k-slice / D row-group
    const int b0   = blockIdx.x * GRP;

    // ---- build sigma table (exact centers; one-time trans use) ----
    for (int i = tid; i < TBL; i += BLOCKT) {
        const float dc = (i + 0.5f) * (1.0f / TSCAL) - 12.0f;
        const float e  = __builtin_amdgcn_exp2f(dc);
        tbl[i] = (_Float16)__builtin_amdgcn_rcpf(e + 1.0f);
    }

    // ---- A-frags: sigma-folded (-2W), KPRE-prescaled; layer-0 x natural ----
    f16x8 wain[2], waown[2];
    #pragma unroll
    for (int tile = 0; tile < 2; ++tile) {
        const int j = 16 * tile + n;
        #pragma unroll
        for (int i = 0; i < 8; ++i) {
            const int kap = 8 * qq + i;
            const int nu  = nu_of(kap);
            float vi = 0.f, vo = 0.f;
            if (j < HH) {
                if (l == 0) { if (kap < DD) vi =  wi0[j * DD + kap]; }
                else        { if (nu  < HH) vi = -2.f * wih[(l - 1) * 900 + j * HH + nu]; }
                if (nu < HH) vo = -2.f * whh[l * 900 + j * HH + nu];
            }
            wain[tile][i]  = (_Float16)(vi * KPRE);
            waown[tile][i] = (_Float16)(vo * KPRE);
        }
    }
    // ---- bias C-init: KPRE*(b_ih + b_hh + rowsum(Whh) + (l>0 ? rowsum(Wih) : 0))
    f32x4 cb[2];
    #pragma unroll
    for (int tile = 0; tile < 2; ++tile)
        #pragma unroll
        for (int r = 0; r < 4; ++r) {
            const int j2 = 16 * tile + 4 * qq + r;
            float v = 0.f;
            if (j2 < HH) {
                v = bih[l * HH + j2] + bhh[l * HH + j2];
                for (int k = 0; k < HH; ++k) v += whh[l * 900 + j2 * HH + k];
                if (l > 0)
                    for (int k = 0; k < HH; ++k) v += wih[(l - 1) * 900 + j2 * HH + k];
            }
            cb[tile][r] = v * KPRE;
        }
    // ---- FC folded: out = (sum(fcw)+fcb) + sum(-2 fcw * sigma)
    float fcl[8];
    #pragma unroll
    for (int i = 0; i < 8; ++i) {
        const int nu = nu_of(8 * qq + i);
        fcl[i] = (nu < HH) ? -2.f * fcw[nu] : 0.f;
    }
    float fbv = fcb[0];
    for (int k = 0; k < HH; ++k) fbv += fcw[k];

    // ---- wave-0 x prefetch: raw float4 for the NEXT 4-timestep half ----
    float4 xb[HC][2];
    const float4* x4 = (const float4*)x;
    const size_t xbase = (size_t)(b0 + n) * TT * 4;
    if (l == 0 && qq < 2) {
        #pragma unroll
        for (int cc = 0; cc < HC; ++cc) {          // half 0 (t = 0..3)
            xb[cc][0] = x4[xbase + cc * 4 + 2 * qq];
            xb[cc][1] = x4[xbase + cc * 4 + 2 * qq + 1];
        }
    }

    // LDS link bases (halfs); per-lane 16B slot at lane*8
    _Float16* lin_r = link + (l - 1) * LINK_H + lane * 8;  // valid for l>0
    _Float16* lin_w = link + l * LINK_H + lane * 8;        // valid for l<9

    // recurrent state: sigma-encoded, sigma(h=0) = 0.5
    f16x8 bown;
    #pragma unroll
    for (int i = 0; i < 8; ++i) bown[i] = (_Float16)0.5f;

    if (tid < 2 * LL) flg[tid] = 0u;
    __syncthreads();                  // the only block-wide barrier

    for (int pb = 0; pb < NCH; pb += RING) {
        #pragma unroll
        for (int sl = 0; sl < RING; ++sl) {       // sl literal -> static offsets
            const int pt = pb + sl;

            // producer slot-gate: slot sl held chunk pt-RING; consumer must
            // have consumed it (cons >= pt-RING+1)
            if (l < LL - 1 && pt >= RING)
                wait_ge(&flg[LL + l + 1], (unsigned)(pt - RING + 1));
            // consumer chunk poll: producer finished chunk pt entirely
            if (l > 0)
                wait_ge(&flg[l - 1], (unsigned)(pt + 1));

            #pragma unroll
            for (int h = 0; h < 2; ++h) {         // two 4-cc halves
                // ---- load/convert input half ----
                U128 binu[HC];
                if (l == 0) {
                    #pragma unroll
                    for (int cc = 0; cc < HC; ++cc) {
                        if (qq < 2) {
                            const float4 u = xb[cc][0], v = xb[cc][1];
                            binu[cc].p[0] = (h2)__builtin_amdgcn_cvt_pkrtz(u.x, u.y);
                            binu[cc].p[1] = (h2)__builtin_amdgcn_cvt_pkrtz(u.z, u.w);
                            binu[cc].p[2] = (h2)__builtin_amdgcn_cvt_pkrtz(v.x, v.y);
                            binu[cc].p[3] = (h2)__builtin_amdgcn_cvt_pkrtz(v.z, v.w);
                            const int gh = pt * 2 + h + 1;     // next half index
                            if (gh < TT / HC) {                // rolling refill
                                const int tn = gh * HC + cc;
                                xb[cc][0] = x4[xbase + tn * 4 + 2 * qq];
                                xb[cc][1] = x4[xbase + tn * 4 + 2 * qq + 1];
                            }
                        } else {
                            binu[cc].u = uint4{0u, 0u, 0u, 0u};
                        }
                    }
                } else {
                    #pragma unroll
                    for (int cc = 0; cc < HC; ++cc)
                        binu[cc].u = *(const uint4*)(lin_r + sl * SL_H + h * HALF_H
                                                     + cc * CC_H);
                }

                // ---- input-side MFMAs: independent, issue early ----
                f32x4 dp0[HC], dp1[HC];
                #pragma unroll
                for (int cc = 0; cc < HC; ++cc) {
                    dp0[cc] = __builtin_amdgcn_mfma_f32_16x16x32_f16(wain[0], binu[cc].h, cb[0], 0, 0, 0);
                    dp1[cc] = __builtin_amdgcn_mfma_f32_16x16x32_f16(wain[1], binu[cc].h, cb[1], 0, 0, 0);
                }
                // publish consumption once per chunk, after ALL 8 reads issued
                if (h == 1 && l > 0 && lane == 0)
                    publish(&flg[LL + l], (unsigned)(pt + 1));

                // ---- serial own-chain: mfma -> table-sigma -> pack -> write ----
                #pragma unroll
                for (int cc = 0; cc < HC; ++cc) {
                    const f32x4 d0 = __builtin_amdgcn_mfma_f32_16x16x32_f16(waown[0], bown, dp0[cc], 0, 0, 0);
                    const f32x4 d1 = __builtin_amdgcn_mfma_f32_16x16x32_f16(waown[1], bown, dp1[cc], 0, 0, 0);
                    // 8 independent gathers (one LDS latency, not 8) + shift-or pack
                    const unsigned s00 = tbu[sidx(d0[0])], s01 = tbu[sidx(d0[1])];
                    const unsigned s02 = tbu[sidx(d0[2])], s03 = tbu[sidx(d0[3])];
                    const unsigned s10 = tbu[sidx(d1[0])], s11 = tbu[sidx(d1[1])];
                    const unsigned s12 = tbu[sidx(d1[2])], s13 = tbu[sidx(d1[3])];
                    U128 uu;
                    uu.u = uint4{ s00 | (s01 << 16), s02 | (s03 << 16),
                                  s10 | (s11 << 16), s12 | (s13 << 16) };
                    bown = uu.h;
                    if (l < LL - 1)
                        *(uint4*)(lin_w + sl * SL_H + h * HALF_H + cc * CC_H) = uu.u;
                }
            }
            // publish production once per chunk (lgkm drain covers ds_writes)
            if (l < LL - 1 && lane == 0)
                publish(&flg[l], (unsigned)(pt + 1));
        }
    }

    // ---- FC on sigma_9(T-1): out = (sum fcw + fcb) + sum(-2 fcw * sigma) ----
    if (l == LL - 1) {
        float v = 0.f;
        #pragma unroll
        for (int i = 0; i < 8; ++i) v = fmaf((float)bown[i], fcl[i], v);
        v += __shfl_xor(v, 16);      // combine the four qq k-slices
        v += __shfl_xor(v, 32);
        if (qq == 0) out[b0 + n] = v + fbv;
    }
}

extern "C" void kernel_launch(void* const* d_in, const int* in_sizes, int n_in,
                              void* d_out, int out_size, void* d_ws, size_t ws_size,
                              hipStream_t stream) {
    const float* x   = (const float*)d_in[0];
    const float* wi0 = (const float*)d_in[1];
    const float* wih = (const float*)d_in[2];
    const float* whh = (const float*)d_in[3];
    const float* bih = (const float*)d_in[4];
    const float* bhh = (const float*)d_in[5];
    const float* fcw = (const float*)d_in[6];
    const float* fcb = (const float*)d_in[7];
    float* out = (float*)d_out;

    const size_t lds_bytes =
        (size_t)(TBL + (LL - 1) * LINK_H) * sizeof(_Float16); // 159744 B
    hipFuncSetAttribute((const void*)rnn_tbl,
                        hipFuncAttributeMaxDynamicSharedMemorySize,
                        (int)lds_bytes);

    rnn_tbl<<<1024 / GRP, BLOCKT, lds_bytes, stream>>>(x, wi0, wih, whh,
                                                       bih, bhh, fcw, fcb, out);
}

// Round 18
// 201.461 us; speedup vs baseline: 1.1288x; 1.1288x over previous
//
#include <hip/hip_runtime.h>

#define TT 512
#define DD 16
#define HH 30
#define LL 10
#define CHK 8                 // timesteps per chunk (sync granularity)
#define HC  4                 // timesteps per half (inner body)
#define NCH (TT / CHK)        // 64 chunks
#define RING 2                // slots per link; slack = 8..16 timesteps
#define GRP 16                // batches per block = MFMA N
#define BLOCKT (LL * 64)      // 640 threads, wave = layer
#define KPRE 2.885390081777927f   // 2*log2(e)

// LDS strides in halfs: per-(slot,half,cc) tile = 64 lanes x 8 halfs
#define CC_H   512
#define HALF_H (HC * CC_H)    // 2048
#define SL_H   (CHK * CC_H)   // 4096
#define LINK_H (RING * SL_H)  // 8192 halfs = 16 KB; 9 links = 147456 B

typedef _Float16 f16x8 __attribute__((ext_vector_type(8)));
typedef _Float16 h2    __attribute__((ext_vector_type(2)));
typedef float    f32x4 __attribute__((ext_vector_type(4)));

union U128 { uint4 u; f16x8 h; h2 p[4]; };

// sigma(d) = 1/(exp2(d)+1);  h = 1 - 2*sigma folded into consumer weights/bias.
__device__ __forceinline__ float sigma_e(float d) {
    const float e = __builtin_amdgcn_exp2f(d);
    return __builtin_amdgcn_rcpf(e + 1.0f);
}

// k-position -> natural neuron permutation (MFMA D == next B-own fragment).
__device__ __forceinline__ int nu_of(int k) {
    return 16 * ((k >> 2) & 1) + 4 * (k >> 3) + (k & 3);
}

__device__ __forceinline__ void wait_ge(unsigned* f, unsigned tgt) {
    while (__hip_atomic_load(f, __ATOMIC_ACQUIRE,
                             __HIP_MEMORY_SCOPE_WORKGROUP) < tgt)
        __builtin_amdgcn_s_sleep(1);
}

// Hand-rolled release: order our LDS ops before the LDS flag store, and
// NOTHING else -- never drains vmcnt (wave-0 global prefetch stays in flight).
__device__ __forceinline__ void publish(unsigned* f, unsigned v) {
    __builtin_amdgcn_sched_barrier(0);
    asm volatile("s_waitcnt lgkmcnt(0)" ::: "memory");
    __hip_atomic_store(f, v, __ATOMIC_RELAXED, __HIP_MEMORY_SCOPE_WORKGROUP);
}

__global__ __launch_bounds__(BLOCKT) void rnn_c8(
    const float* __restrict__ x,   const float* __restrict__ wi0,
    const float* __restrict__ wih, const float* __restrict__ whh,
    const float* __restrict__ bih, const float* __restrict__ bhh,
    const float* __restrict__ fcw, const float* __restrict__ fcb,
    float* __restrict__ out)
{
    extern __shared__ __align__(16) _Float16 link[]; // [LL-1][RING][CHK][512h]
    __shared__ unsigned flg[2 * LL];  // [l]=produced(link l), [LL+l]=consumed(link l-1)

    const int tid  = threadIdx.x;
    const int l    = tid >> 6;        // wave == layer
    const int lane = tid & 63;
    const int n    = lane & 15;       // batch-in-group
    const int qq   = lane >> 4;       // k-slice / D row-group
    const int b0   = blockIdx.x * GRP;

    // ---- A-frags: sigma-folded (-2W), KPRE-prescaled; layer-0 x natural ----
    f16x8 wain[2], waown[2];
    #pragma unroll
    for (int tile = 0; tile < 2; ++tile) {
        const int j = 16 * tile + n;
        #pragma unroll
        for (int i = 0; i < 8; ++i) {
            const int kap = 8 * qq + i;
            const int nu  = nu_of(kap);
            float vi = 0.f, vo = 0.f;
            if (j < HH) {
                if (l == 0) { if (kap < DD) vi =  wi0[j * DD + kap]; }
                else        { if (nu  < HH) vi = -2.f * wih[(l - 1) * 900 + j * HH + nu]; }
                if (nu < HH) vo = -2.f * whh[l * 900 + j * HH + nu];
            }
            wain[tile][i]  = (_Float16)(vi * KPRE);
            waown[tile][i] = (_Float16)(vo * KPRE);
        }
    }
    // ---- bias C-init: KPRE*(b_ih + b_hh + rowsum(Whh) + (l>0 ? rowsum(Wih) : 0))
    f32x4 cb[2];
    #pragma unroll
    for (int tile = 0; tile < 2; ++tile)
        #pragma unroll
        for (int r = 0; r < 4; ++r) {
            const int j2 = 16 * tile + 4 * qq + r;
            float v = 0.f;
            if (j2 < HH) {
                v = bih[l * HH + j2] + bhh[l * HH + j2];
                for (int k = 0; k < HH; ++k) v += whh[l * 900 + j2 * HH + k];
                if (l > 0)
                    for (int k = 0; k < HH; ++k) v += wih[(l - 1) * 900 + j2 * HH + k];
            }
            cb[tile][r] = v * KPRE;
        }
    // ---- FC folded: out = (sum(fcw)+fcb) + sum(-2 fcw * sigma)
    float fcl[8];
    #pragma unroll
    for (int i = 0; i < 8; ++i) {
        const int nu = nu_of(8 * qq + i);
        fcl[i] = (nu < HH) ? -2.f * fcw[nu] : 0.f;
    }
    float fbv = fcb[0];
    for (int k = 0; k < HH; ++k) fbv += fcw[k];

    // ---- wave-0 x prefetch: xb = raw float4 for the NEXT 4-timestep half ----
    float4 xb[HC][2];
    const float4* x4 = (const float4*)x;
    const size_t xbase = (size_t)(b0 + n) * TT * 4;
    if (l == 0 && qq < 2) {
        #pragma unroll
        for (int cc = 0; cc < HC; ++cc) {          // half 0 (t = 0..3)
            xb[cc][0] = x4[xbase + cc * 4 + 2 * qq];
            xb[cc][1] = x4[xbase + cc * 4 + 2 * qq + 1];
        }
    }

    // LDS link bases (halfs); per-lane 16B slot at lane*8
    _Float16* lin_r = link + (l - 1) * LINK_H + lane * 8;  // valid for l>0
    _Float16* lin_w = link + l * LINK_H + lane * 8;        // valid for l<9

    // recurrent state: sigma-encoded, sigma(h=0) = 0.5
    f16x8 bown;
    #pragma unroll
    for (int i = 0; i < 8; ++i) bown[i] = (_Float16)0.5f;

    if (tid < 2 * LL) flg[tid] = 0u;
    __syncthreads();                  // the only block-wide barrier

    for (int pb = 0; pb < NCH; pb += RING) {
        #pragma unroll
        for (int sl = 0; sl < RING; ++sl) {       // sl literal -> static offsets
            const int pt = pb + sl;

            // producer slot-gate: slot sl held chunk pt-RING; consumer must
            // have consumed it (cons >= pt-RING+1)
            if (l < LL - 1 && pt >= RING)
                wait_ge(&flg[LL + l + 1], (unsigned)(pt - RING + 1));
            // consumer chunk poll: producer finished chunk pt entirely
            if (l > 0)
                wait_ge(&flg[l - 1], (unsigned)(pt + 1));

            #pragma unroll
            for (int h = 0; h < 2; ++h) {         // two R13-style 4-cc halves
                // ---- load/convert input half ----
                U128 binu[HC];
                if (l == 0) {
                    #pragma unroll
                    for (int cc = 0; cc < HC; ++cc) {
                        if (qq < 2) {
                            const float4 u = xb[cc][0], v = xb[cc][1];
                            binu[cc].p[0] = (h2)__builtin_amdgcn_cvt_pkrtz(u.x, u.y);
                            binu[cc].p[1] = (h2)__builtin_amdgcn_cvt_pkrtz(u.z, u.w);
                            binu[cc].p[2] = (h2)__builtin_amdgcn_cvt_pkrtz(v.x, v.y);
                            binu[cc].p[3] = (h2)__builtin_amdgcn_cvt_pkrtz(v.z, v.w);
                            const int gh = pt * 2 + h + 1;     // next half index
                            if (gh < TT / HC) {                // rolling refill
                                const int tn = gh * HC + cc;
                                xb[cc][0] = x4[xbase + tn * 4 + 2 * qq];
                                xb[cc][1] = x4[xbase + tn * 4 + 2 * qq + 1];
                            }
                        } else {
                            binu[cc].u = uint4{0u, 0u, 0u, 0u};
                        }
                    }
                } else {
                    #pragma unroll
                    for (int cc = 0; cc < HC; ++cc)
                        binu[cc].u = *(const uint4*)(lin_r + sl * SL_H + h * HALF_H
                                                     + cc * CC_H);
                }

                // ---- input-side MFMAs: independent, issue early ----
                f32x4 dp0[HC], dp1[HC];
                #pragma unroll
                for (int cc = 0; cc < HC; ++cc) {
                    dp0[cc] = __builtin_amdgcn_mfma_f32_16x16x32_f16(wain[0], binu[cc].h, cb[0], 0, 0, 0);
                    dp1[cc] = __builtin_amdgcn_mfma_f32_16x16x32_f16(wain[1], binu[cc].h, cb[1], 0, 0, 0);
                }
                // publish consumption once per chunk, after ALL 8 reads issued
                // (the publish's lgkm drain covers them)
                if (h == 1 && l > 0 && lane == 0)
                    publish(&flg[LL + l], (unsigned)(pt + 1));

                // ---- serial own-chain: mfma -> sigma -> pack -> ds_write ----
                #pragma unroll
                for (int cc = 0; cc < HC; ++cc) {
                    const f32x4 d0 = __builtin_amdgcn_mfma_f32_16x16x32_f16(waown[0], bown, dp0[cc], 0, 0, 0);
                    const f32x4 d1 = __builtin_amdgcn_mfma_f32_16x16x32_f16(waown[1], bown, dp1[cc], 0, 0, 0);
                    U128 uu;
                    uu.p[0] = (h2)__builtin_amdgcn_cvt_pkrtz(sigma_e(d0[0]), sigma_e(d0[1]));
                    uu.p[1] = (h2)__builtin_amdgcn_cvt_pkrtz(sigma_e(d0[2]), sigma_e(d0[3]));
                    uu.p[2] = (h2)__builtin_amdgcn_cvt_pkrtz(sigma_e(d1[0]), sigma_e(d1[1]));
                    uu.p[3] = (h2)__builtin_amdgcn_cvt_pkrtz(sigma_e(d1[2]), sigma_e(d1[3]));
                    bown = uu.h;
                    if (l < LL - 1)
                        *(uint4*)(lin_w + sl * SL_H + h * HALF_H + cc * CC_H) = uu.u;
                }
            }
            // publish production once per chunk (lgkm drain covers ds_writes)
            if (l < LL - 1 && lane == 0)
                publish(&flg[l], (unsigned)(pt + 1));
        }
    }

    // ---- FC on sigma_9(T-1): out = (sum fcw + fcb) + sum(-2 fcw * sigma) ----
    if (l == LL - 1) {
        float v = 0.f;
        #pragma unroll
        for (int i = 0; i < 8; ++i) v = fmaf((float)bown[i], fcl[i], v);
        v += __shfl_xor(v, 16);      // combine the four qq k-slices
        v += __shfl_xor(v, 32);
        if (qq == 0) out[b0 + n] = v + fbv;
    }
}

extern "C" void kernel_launch(void* const* d_in, const int* in_sizes, int n_in,
                              void* d_out, int out_size, void* d_ws, size_t ws_size,
                              hipStream_t stream) {
    const float* x   = (const float*)d_in[0];
    const float* wi0 = (const float*)d_in[1];
    const float* wih = (const float*)d_in[2];
    const float* whh = (const float*)d_in[3];
    const float* bih = (const float*)d_in[4];
    const float* bhh = (const float*)d_in[5];
    const float* fcw = (const float*)d_in[6];
    const float* fcb = (const float*)d_in[7];
    float* out = (float*)d_out;

    const size_t lds_bytes = (size_t)(LL - 1) * LINK_H * sizeof(_Float16); // 147456 B
    hipFuncSetAttribute((const void*)rnn_c8,
                        hipFuncAttributeMaxDynamicSharedMemorySize,
                        (int)lds_bytes);

    rnn_c8<<<1024 / GRP, BLOCKT, lds_bytes, stream>>>(x, wi0, wih, whh,
                                                      bih, bhh, fcw, fcb, out);
}